// Round 12
// baseline (145.482 us; speedup 1.0000x reference)
//
#include <hip/hip_runtime.h>
#include <math.h>

// Problem constants (B=1)
#define TT 2048   // sequence length
#define CC 1024   // channels
#define HH 16     // heads
#define DD 64     // head dim
#define N3 3072   // 3*C

typedef unsigned short u16;
typedef __bf16 bf16x8 __attribute__((ext_vector_type(8)));
typedef float f32x4 __attribute__((ext_vector_type(4)));
typedef unsigned short u16x8 __attribute__((ext_vector_type(8)));
typedef const __attribute__((address_space(1))) void gv_t;
typedef __attribute__((address_space(3))) void lv_t;

__device__ __forceinline__ u16 bf16_rne(float f) {
  unsigned u = __float_as_uint(f);
  u += 0x7FFFu + ((u >> 16) & 1u);
  return (u16)(u >> 16);
}
__device__ __forceinline__ float bf16f(u16 h) {
  return __uint_as_float(((unsigned)h) << 16);
}
__device__ __forceinline__ bf16x8 ldfrag(const u16* p) {
  return __builtin_bit_cast(bf16x8, *(const u16x8*)p);
}
#if __has_builtin(__builtin_amdgcn_cvt_pk_bf16_f32)
__device__ __forceinline__ unsigned pk_bf16(float a, float b) {
  return __builtin_bit_cast(unsigned, __builtin_amdgcn_cvt_pk_bf16_f32(a, b));
}
#else
__device__ __forceinline__ unsigned pk_bf16(float a, float b) {
  return (unsigned)bf16_rne(a) | ((unsigned)bf16_rne(b) << 16);
}
#endif

// ---- prep: x->bf16 (A) + w_qkv^T (B) + w_proj^T (C) + sincos table (D) ----
// Transposes: 64k x 32n tiles, float4 vectorized reads, ushort4 LDS writes
// (pad 36 keeps 8B alignment), ushort4 coalesced global writes.
__global__ __launch_bounds__(256) void k_prep(
    const float* __restrict__ x, const float* __restrict__ w_qkv,
    const float* __restrict__ w_proj, u16* __restrict__ xb,
    u16* __restrict__ wqkvT, u16* __restrict__ wprojT,
    float2* __restrict__ scos /*[2048][32]*/) {
  __shared__ u16 tile[64][36];
  const int bi = blockIdx.x, tid = threadIdx.x;
  if (bi < 2048) {                       // A: cvt x
    int i = bi * 256 + tid;
    float4 v = ((const float4*)x)[i];
    ushort4 r;
    r.x = bf16_rne(v.x); r.y = bf16_rne(v.y); r.z = bf16_rne(v.z); r.w = bf16_rne(v.w);
    ((ushort4*)xb)[i] = r;
    return;
  }
  if (bi >= 2048 + 1536 + 512) {         // D: sincos table [t][i]
    int idx = (bi - 4096) * 256 + tid;   // over 2048*32
    int t = idx >> 5, i = idx & 31;
    float inv_freq = exp2f(-(float)(2 * i) * (1.0f / 64.0f) * 13.2877123795494f);
    float ang = (float)t * inv_freq;
    scos[idx] = make_float2(sinf(ang), cosf(ang));
    return;
  }
  const float* w; u16* wt; int K, N, n0, k0;
  if (bi < 2048 + 1536) {                // B: w_qkv [1024][3072] -> T
    int b = bi - 2048; w = w_qkv; wt = wqkvT; K = CC; N = N3;
    k0 = (b / 96) * 64; n0 = (b % 96) * 32;
  } else {                               // C: w_proj -> T
    int b = bi - 3584; w = w_proj; wt = wprojT; K = CC; N = CC;
    k0 = (b >> 5) * 64; n0 = (b & 31) * 32;
  }
  const int c = tid & 7, kr0 = tid >> 3;    // (8 float4-chunks, 32 rows)
#pragma unroll
  for (int p = 0; p < 2; p++) {
    int k = kr0 + p * 32;
    float4 v = *(const float4*)&w[(size_t)(k0 + k) * N + n0 + c * 4];
    ushort4 o;
    o.x = bf16_rne(v.x); o.y = bf16_rne(v.y); o.z = bf16_rne(v.z); o.w = bf16_rne(v.w);
    *(ushort4*)&tile[k][c * 4] = o;
  }
  __syncthreads();
  const int kc = tid & 15, nr = tid >> 4;   // (16 k-groups, 16 n-rows)
#pragma unroll
  for (int jn = 0; jn < 2; jn++) {
    int n = nr + (jn << 4);
    ushort4 o;
    o.x = tile[kc * 4 + 0][n];
    o.y = tile[kc * 4 + 1][n];
    o.z = tile[kc * 4 + 2][n];
    o.w = tile[kc * 4 + 3][n];
    *(ushort4*)&wt[(size_t)(n0 + n) * K + k0 + kc * 4] = o;
  }
}

// swizzled frag read: row rr, 8-u16 chunk c8 -> LDS chunk c8 ^ (rr&7)
__device__ __forceinline__ bf16x8 rdsw(const u16* base, int rr, int c8) {
  return ldfrag(&base[rr * 64 + ((c8 ^ (rr & 7)) << 3)]);
}

// ---- qkv GEMM: 128x96 tile (grid 32x16 = 512 blocks = 2/CU), BK=64,
// double-buffered 2-phase (stage(t+1) overlaps compute(t), ONE barrier/iter),
// swizzled LDS, fused RoPE + head-split epilogue; v-slice stored via
// wave-private LDS transpose -> fully coalesced 128B rows ----
__global__ __launch_bounds__(256) void k_gemm_qkv(
    const u16* __restrict__ A, const u16* __restrict__ Bt,
    const float2* __restrict__ scos /*[t][i]*/, u16* __restrict__ qr,
    u16* __restrict__ kr, u16* __restrict__ vt, int M, int N, int K) {
  __shared__ u16 As[2][128 * 64];   // 32 KB, rows of 64 u16, chunk-swizzled
  __shared__ u16 Bs[2][96 * 64];    // 24 KB
  const int tid = threadIdx.x;
  const int lane = tid & 63, w = tid >> 6;
  const int col = lane & 15, quad = lane >> 4;
  const int wm = w >> 1, wn = w & 1;
  const int tm = blockIdx.y * 128, tn = blockIdx.x * 96;

  const int lr = lane >> 3;                    // sub-row 0..7 (swizzle key)
  const int soff = ((lane & 7) ^ lr) << 3;     // u16 offset of source chunk

  f32x4 acc[12];
#pragma unroll
  for (int i = 0; i < 12; i++) acc[i] = (f32x4){0.f, 0.f, 0.f, 0.f};

  auto stage = [&](int k0, int buf) {
#pragma unroll
    for (int i = 0; i < 4; i++) {
      const int rbase = w * 32 + i * 8;
      __builtin_amdgcn_global_load_lds(
          (gv_t*)(A + (size_t)(tm + rbase + lr) * K + k0 + soff),
          (lv_t*)(&As[buf][rbase * 64]), 16, 0, 0);
    }
#pragma unroll
    for (int i = 0; i < 3; i++) {
      const int rbase = w * 24 + i * 8;
      __builtin_amdgcn_global_load_lds(
          (gv_t*)(Bt + (size_t)(tn + rbase + lr) * K + k0 + soff),
          (lv_t*)(&Bs[buf][rbase * 64]), 16, 0, 0);
    }
  };

  stage(0, 0);
  __syncthreads();                             // drain stage(0)
  const int NT = K / 64;                       // 16
  for (int t = 0; t < NT; t++) {
    const int cur = t & 1;
    if (t + 1 < NT) stage((t + 1) * 64, cur ^ 1);  // overlaps compute(t)
#pragma unroll
    for (int kk = 0; kk < 2; kk++) {
      bf16x8 af[4], bf[3];
#pragma unroll
      for (int mt = 0; mt < 4; mt++)
        af[mt] = rdsw(&As[cur][0], wm * 64 + mt * 16 + col, kk * 4 + quad);
#pragma unroll
      for (int nt = 0; nt < 3; nt++)
        bf[nt] = rdsw(&Bs[cur][0], wn * 48 + nt * 16 + col, kk * 4 + quad);
#pragma unroll
      for (int mt = 0; mt < 4; mt++)
#pragma unroll
        for (int nt = 0; nt < 3; nt++)
          acc[mt * 3 + nt] = __builtin_amdgcn_mfma_f32_16x16x32_bf16(af[mt], bf[nt], acc[mt * 3 + nt], 0, 0, 0);
    }
    __syncthreads();                           // drains stage(t+1) after compute
  }
  // After the final barrier every wave is done reading As/Bs -> reuse As as
  // wave-private transpose scratch (16 d x 68-stride u16 per wave = 2176 B).
  u16* scr = ((u16*)As) + w * 1088;

  const int tb = tm + wm * 64;
#pragma unroll
  for (int nt = 0; nt < 3; nt++) {
    const int nn = tn + wn * 48 + nt * 16;     // wave-uniform, 16-aligned
    const int slice = nn >> 10;                // 0=q, 1=k, 2=v (16 | 1024: no straddle)
    const int hh = (nn >> 6) & 15;
    const int db = nn & 63;
    const int d = db + col;
    if (slice < 2) {                           // q/k: RoPE + [H][T][D]
      u16* dst = (slice == 0) ? qr : kr;
      const bool ev = (col & 1) == 0;
      const int i = (db >> 1) + (col >> 1);
#pragma unroll
      for (int mt = 0; mt < 4; mt++)
#pragma unroll
        for (int r = 0; r < 4; r++) {
          int t = tb + mt * 16 + quad * 4 + r;
          float2 sc2 = scos[t * 32 + i];
          float e = acc[mt * 3 + nt][r];
          float pp = __shfl_xor(e, 1);
          float v = ev ? (e * sc2.y - pp * sc2.x) : (pp * sc2.x + e * sc2.y);
          dst[((size_t)(hh * TT + t) << 6) + d] = bf16_rne(v);
        }
    } else {                                   // v: [H][D][T] via LDS transpose
      // write the wave's 16d x 64t sub-tile into scratch [d][t] (stride 68)
#pragma unroll
      for (int mt = 0; mt < 4; mt++)
#pragma unroll
        for (int r = 0; r < 4; r++)
          scr[col * 68 + mt * 16 + quad * 4 + r] = bf16_rne(acc[mt * 3 + nt][r]);
      // same-wave ds_write->ds_read ordering handled by lgkmcnt (no barrier:
      // scratch is wave-private)
#pragma unroll
      for (int i = 0; i < 4; i++) {
        const int dl = quad + i * 4;           // row 0..15 (one row per 16 lanes)
        const int tl = col * 4;                // 0..60
        ushort4 vv = *(const ushort4*)&scr[dl * 68 + tl];
        *(ushort4*)&vt[((size_t)(hh * DD + db + dl)) * TT + tb + tl] = vv;
      }
    }
  }
}

// ---- proj GEMM: 64x64 tile (grid 16x32 = 512 blocks = 2+/CU), BK=64,
// double-buffered 2-phase, swizzled LDS, fp32 out. Wave tile 32x32. ----
__global__ __launch_bounds__(256) void k_gemm_pj(
    const u16* __restrict__ A, const u16* __restrict__ Bt,
    float* __restrict__ C, int M, int N, int K) {
  __shared__ u16 As[2][64 * 64];    // 16 KB
  __shared__ u16 Bs[2][64 * 64];    // 16 KB
  const int tid = threadIdx.x;
  const int lane = tid & 63, w = tid >> 6;
  const int col = lane & 15, quad = lane >> 4;
  const int wm = w >> 1, wn = w & 1;
  const int tm = blockIdx.y * 64, tn = blockIdx.x * 64;

  const int lr = lane >> 3;
  const int soff = ((lane & 7) ^ lr) << 3;

  f32x4 acc[4];
#pragma unroll
  for (int i = 0; i < 4; i++) acc[i] = (f32x4){0.f, 0.f, 0.f, 0.f};

  auto stage = [&](int k0, int buf) {
#pragma unroll
    for (int i = 0; i < 2; i++) {
      const int rbase = w * 16 + i * 8;
      __builtin_amdgcn_global_load_lds(
          (gv_t*)(A + (size_t)(tm + rbase + lr) * K + k0 + soff),
          (lv_t*)(&As[buf][rbase * 64]), 16, 0, 0);
      __builtin_amdgcn_global_load_lds(
          (gv_t*)(Bt + (size_t)(tn + rbase + lr) * K + k0 + soff),
          (lv_t*)(&Bs[buf][rbase * 64]), 16, 0, 0);
    }
  };

  stage(0, 0);
  __syncthreads();
  const int NT = K / 64;
  for (int t = 0; t < NT; t++) {
    const int cur = t & 1;
    if (t + 1 < NT) stage((t + 1) * 64, cur ^ 1);
#pragma unroll
    for (int kk = 0; kk < 2; kk++) {
      bf16x8 af[2], bf[2];
#pragma unroll
      for (int mt = 0; mt < 2; mt++)
        af[mt] = rdsw(&As[cur][0], wm * 32 + mt * 16 + col, kk * 4 + quad);
#pragma unroll
      for (int nt = 0; nt < 2; nt++)
        bf[nt] = rdsw(&Bs[cur][0], wn * 32 + nt * 16 + col, kk * 4 + quad);
#pragma unroll
      for (int mt = 0; mt < 2; mt++)
#pragma unroll
        for (int nt = 0; nt < 2; nt++)
          acc[mt * 2 + nt] = __builtin_amdgcn_mfma_f32_16x16x32_bf16(af[mt], bf[nt], acc[mt * 2 + nt], 0, 0, 0);
    }
    __syncthreads();
  }
#pragma unroll
  for (int mt = 0; mt < 2; mt++)
#pragma unroll
    for (int nt = 0; nt < 2; nt++)
#pragma unroll
      for (int r = 0; r < 4; r++)
        C[(size_t)(tm + wm * 32 + mt * 16 + quad * 4 + r) * N + tn + wn * 32 + nt * 16 + col] =
            acc[mt * 2 + nt][r];
}

// ---- cooperative flash: 1024 blocks = (head, 32-query strip) -> 4 blocks/CU,
// 16 waves/CU; waves split (q-half x key-parity), partial (acc,l) merged via
// LDS (fixed-offset softmax => exact associativity). l on the MFMA pipe
// (B = ones). K staged via global_load_lds; V PREFETCHED TO REGISTERS from
// L2 at tile start (issue-early/consume-late: QK^T+softmax covers latency).
// LDS = Ks 16 + Ps 8 = 24 KB. ----
__global__ __launch_bounds__(256) void k_flash(
    const u16* __restrict__ qr, const u16* __restrict__ kr,
    const u16* __restrict__ vt, u16* __restrict__ attnb /*[T][C]*/) {
  __shared__ u16 Ks[2][64 * 64];      // 16 KB: [parity] 64-key tile
  __shared__ u16 Ps[4][16 * 64];      //  8 KB, wave-private slices

  const int tid = threadIdx.x;
  const int lane = tid & 63, wv = tid >> 6;
  const int col = lane & 15, quad = lane >> 4;

  // balanced block -> (head, 32-q strip): CU c gets ranks {c,63-c,64+c,127-c}
  const int bid = blockIdx.x;                  // 1024 blocks
  const int xcd = bid & 7, slot = bid >> 3;    // slot 0..127
  const int cu = slot & 31, tier = slot >> 5;  // tier 0..3
  const int rank = (tier & 1) ? (tier * 32 + (31 - cu)) : (tier * 32 + cu);
  const int h = xcd * 2 + (rank & 1);
  const int s = rank >> 1;                     // strip 0..63
  const int q0 = s * 32;
  const int nkt = (s >> 1) + 1;                // 64-key tiles covering 0..q0+31
  const int tdiag = s >> 1;                    // only tile needing the mask

  const int qh = wv & 1;                       // q-half (rows q0+qh*16..+16)
  const int kp = wv >> 1;                      // key parity (tiles 2w+kp)

  const u16* Qh = qr + (size_t)h * TT * DD;
  const u16* Kh = kr + (size_t)h * TT * DD;
  const u16* Vh = vt + (size_t)h * DD * TT;    // [d][t]

  const bf16x8 aq0 = ldfrag(&Qh[(size_t)(q0 + qh * 16 + col) * DD + quad * 8]);
  const bf16x8 aq1 = ldfrag(&Qh[(size_t)(q0 + qh * 16 + col) * DD + 32 + quad * 8]);
  const bf16x8 vones = __builtin_bit_cast(bf16x8,
      (u16x8){0x3F80, 0x3F80, 0x3F80, 0x3F80, 0x3F80, 0x3F80, 0x3F80, 0x3F80});

  const int lr = lane >> 3;                    // sub-row 0..7 (swizzle key)
  const int srcoff = ((lane & 7) ^ lr) << 3;

  const f32x4 zero = {0.f, 0.f, 0.f, 0.f};
  f32x4 acc[4] = {zero, zero, zero, zero};
  f32x4 lacc = zero;                           // l[q] on the matrix pipe
  u16* Pb = &Ps[wv][0];

  auto compute = [&](int t, const u16* Kt) {
    // V fragments direct from L2 -- issued FIRST so QK^T+softmax covers the
    // latency (value-identical to the old staged path: V[d=nt*16+col][t..])
    bf16x8 vf[2][4];
#pragma unroll
    for (int kk = 0; kk < 2; kk++)
#pragma unroll
      for (int nt = 0; nt < 4; nt++)
        vf[kk][nt] = ldfrag(&Vh[(size_t)(nt * 16 + col) * TT + t * 64 + kk * 32 + quad * 8]);
    // S = Q K^T
    f32x4 sc[4];
#pragma unroll
    for (int nt = 0; nt < 4; nt++) {
      const int rr = nt * 16 + col;
      sc[nt] = __builtin_amdgcn_mfma_f32_16x16x32_bf16(aq0, rdsw(Kt, rr, quad), zero, 0, 0, 0);
      sc[nt] = __builtin_amdgcn_mfma_f32_16x16x32_bf16(aq1, rdsw(Kt, rr, 4 + quad), sc[nt], 0, 0, 0);
    }
    if (t == tdiag) {                          // causal mask on the edge tile
#pragma unroll
      for (int nt = 0; nt < 4; nt++)
#pragma unroll
        for (int r = 0; r < 4; r++)
          if (t * 64 + nt * 16 + col > q0 + qh * 16 + quad * 4 + r) sc[nt][r] = -1e30f;
    }
    // p = exp(s/8 - 20) via exp2
#pragma unroll
    for (int nt = 0; nt < 4; nt++)
#pragma unroll
      for (int r = 0; r < 4; r++)
        sc[nt][r] = exp2f(fmaf(sc[nt][r], 0.18033688f, -28.8539008f));
    // P -> LDS (C-layout scatter, XOR bank swizzle on 16-col blocks)
#pragma unroll
    for (int nt = 0; nt < 4; nt++) {
      unsigned p01 = pk_bf16(sc[nt][0], sc[nt][1]);
      unsigned p23 = pk_bf16(sc[nt][2], sc[nt][3]);
      u16* base = Pb + quad * 4 * 64 + ((nt ^ quad) << 4) + col;
      base[0 * 64] = (u16)p01;
      base[1 * 64] = (u16)(p01 >> 16);
      base[2 * 64] = (u16)p23;
      base[3 * 64] = (u16)(p23 >> 16);
    }
    // O += P V^T ; l += P . 1 (extra MFMA with B = ones, MFMA pipe is idle)
#pragma unroll
    for (int kk = 0; kk < 2; kk++) {
      int sb = (kk * 2 + (quad >> 1)) ^ (col >> 2);
      bf16x8 ap = ldfrag(&Pb[col * 64 + (sb << 4) + ((quad & 1) << 3)]);
#pragma unroll
      for (int nt = 0; nt < 4; nt++)
        acc[nt] = __builtin_amdgcn_mfma_f32_16x16x32_bf16(ap, vf[kk][nt], acc[nt], 0, 0, 0);
      lacc = __builtin_amdgcn_mfma_f32_16x16x32_bf16(ap, vones, lacc, 0, 0, 0);
    }
  };

  const int nw = (nkt + 1) >> 1;               // 2-tile windows
  for (int w = 0; w < nw; w++) {
    __syncthreads();                           // prior compute done with Ks
#pragma unroll
    for (int j = 0; j < 2; j++) {              // stage K tiles 2w, 2w+1
      const int t = 2 * w + j;
      if (t < nkt) {
#pragma unroll
        for (int i = 0; i < 2; i++) {
          const int rbase = wv * 16 + i * 8;
          __builtin_amdgcn_global_load_lds(
              (gv_t*)(Kh + (size_t)(t * 64 + rbase + lr) * DD + srcoff),
              (lv_t*)(&Ks[j][rbase * 64]), 16, 0, 0);
        }
      }
    }
    __syncthreads();                           // staged (vmcnt drained)
    const int t = 2 * w + kp;
    if (t < nkt) compute(t, Ks[kp]);
  }

  // merge key-parity partials: waves 2,3 -> waves 0,1 (plain sums: associative)
  float* mbuf = (float*)&Ks[0][0];             // 2 x 1344 floats <= 16 KB
  __syncthreads();                             // computes done; Ks reusable
  if (kp == 1) {
    float* mb = mbuf + qh * 1344;
#pragma unroll
    for (int i = 0; i < 4; i++)
#pragma unroll
      for (int r = 0; r < 4; r++) mb[lane * 20 + i * 4 + r] = acc[i][r];
#pragma unroll
    for (int r = 0; r < 4; r++) mb[lane * 20 + 16 + r] = lacc[r];
  }
  __syncthreads();
  if (kp == 0) {
    float* mb = mbuf + qh * 1344;
#pragma unroll
    for (int i = 0; i < 4; i++)
#pragma unroll
      for (int r = 0; r < 4; r++) acc[i][r] += mb[lane * 20 + i * 4 + r];
#pragma unroll
    for (int r = 0; r < 4; r++) lacc[r] += mb[lane * 20 + 16 + r];
    // lacc already holds the full row sum (MFMA summed all 64 keys/tile,
    // replicated across cols) -> no shfl reduce needed
    float inv[4];
#pragma unroll
    for (int r = 0; r < 4; r++) inv[r] = 1.f / lacc[r];
#pragma unroll
    for (int nt = 0; nt < 4; nt++)
#pragma unroll
      for (int r = 0; r < 4; r++) {
        int q = q0 + qh * 16 + quad * 4 + r;
        attnb[(size_t)q * CC + h * DD + nt * 16 + col] = bf16_rne(acc[nt][r] * inv[r]);
      }
  }
}

extern "C" void kernel_launch(void* const* d_in, const int* in_sizes, int n_in,
                              void* d_out, int out_size, void* d_ws, size_t ws_size,
                              hipStream_t stream) {
  const float* x      = (const float*)d_in[0];  // [2048][1024]
  const float* w_qkv  = (const float*)d_in[1];  // [1024][3072]
  const float* w_proj = (const float*)d_in[2];  // [1024][1024]
  float* out = (float*)d_out;                   // [2048][1024] fp32

  char* p = (char*)d_ws;
  u16* xb      = (u16*)p;    p += (size_t)TT * CC * 2;
  u16* wqkvT   = (u16*)p;    p += (size_t)N3 * CC * 2;
  u16* wprojT  = (u16*)p;    p += (size_t)CC * CC * 2;
  float2* scos = (float2*)p; p += (size_t)TT * 32 * 8;
  u16* qr      = (u16*)p;    p += (size_t)HH * TT * DD * 2;
  u16* kr      = (u16*)p;    p += (size_t)HH * TT * DD * 2;
  u16* vt      = (u16*)p;    p += (size_t)HH * DD * TT * 2;
  u16* attnb   = (u16*)p;    p += (size_t)TT * CC * 2;

  k_prep<<<2048 + 1536 + 512 + 256, 256, 0, stream>>>(x, w_qkv, w_proj, xb, wqkvT, wprojT, scos);
  k_gemm_qkv<<<dim3(N3 / 96, TT / 128), 256, 0, stream>>>(xb, wqkvT, scos, qr, kr, vt, TT, N3, CC);
  k_flash<<<1024, 256, 0, stream>>>(qr, kr, vt, attnb);
  k_gemm_pj<<<dim3(CC / 64, TT / 64), 256, 0, stream>>>(attnb, wprojT, out, TT, CC, CC);
}

// Round 13
// 133.642 us; speedup vs baseline: 1.0886x; 1.0886x over previous
//
#include <hip/hip_runtime.h>
#include <math.h>

// Problem constants (B=1)
#define TT 2048   // sequence length
#define CC 1024   // channels
#define HH 16     // heads
#define DD 64     // head dim
#define N3 3072   // 3*C

typedef unsigned short u16;
typedef __bf16 bf16x8 __attribute__((ext_vector_type(8)));
typedef float f32x4 __attribute__((ext_vector_type(4)));
typedef unsigned short u16x8 __attribute__((ext_vector_type(8)));
typedef const __attribute__((address_space(1))) void gv_t;
typedef __attribute__((address_space(3))) void lv_t;

__device__ __forceinline__ u16 bf16_rne(float f) {
  unsigned u = __float_as_uint(f);
  u += 0x7FFFu + ((u >> 16) & 1u);
  return (u16)(u >> 16);
}
__device__ __forceinline__ float bf16f(u16 h) {
  return __uint_as_float(((unsigned)h) << 16);
}
__device__ __forceinline__ bf16x8 ldfrag(const u16* p) {
  return __builtin_bit_cast(bf16x8, *(const u16x8*)p);
}
#if __has_builtin(__builtin_amdgcn_cvt_pk_bf16_f32)
__device__ __forceinline__ unsigned pk_bf16(float a, float b) {
  return __builtin_bit_cast(unsigned, __builtin_amdgcn_cvt_pk_bf16_f32(a, b));
}
#else
__device__ __forceinline__ unsigned pk_bf16(float a, float b) {
  return (unsigned)bf16_rne(a) | ((unsigned)bf16_rne(b) << 16);
}
#endif

// ---- prep: x->bf16 (A) + w_qkv^T (B) + w_proj^T (C) + sincos table (D) ----
// Transposes: 64k x 32n tiles, float4 vectorized reads, ushort4 LDS writes
// (pad 36 keeps 8B alignment), ushort4 coalesced global writes.
__global__ __launch_bounds__(256) void k_prep(
    const float* __restrict__ x, const float* __restrict__ w_qkv,
    const float* __restrict__ w_proj, u16* __restrict__ xb,
    u16* __restrict__ wqkvT, u16* __restrict__ wprojT,
    float2* __restrict__ scos /*[2048][32]*/) {
  __shared__ u16 tile[64][36];
  const int bi = blockIdx.x, tid = threadIdx.x;
  if (bi < 2048) {                       // A: cvt x
    int i = bi * 256 + tid;
    float4 v = ((const float4*)x)[i];
    ushort4 r;
    r.x = bf16_rne(v.x); r.y = bf16_rne(v.y); r.z = bf16_rne(v.z); r.w = bf16_rne(v.w);
    ((ushort4*)xb)[i] = r;
    return;
  }
  if (bi >= 2048 + 1536 + 512) {         // D: sincos table [t][i]
    int idx = (bi - 4096) * 256 + tid;   // over 2048*32
    int t = idx >> 5, i = idx & 31;
    float inv_freq = exp2f(-(float)(2 * i) * (1.0f / 64.0f) * 13.2877123795494f);
    float ang = (float)t * inv_freq;
    scos[idx] = make_float2(sinf(ang), cosf(ang));
    return;
  }
  const float* w; u16* wt; int K, N, n0, k0;
  if (bi < 2048 + 1536) {                // B: w_qkv [1024][3072] -> T
    int b = bi - 2048; w = w_qkv; wt = wqkvT; K = CC; N = N3;
    k0 = (b / 96) * 64; n0 = (b % 96) * 32;
  } else {                               // C: w_proj -> T
    int b = bi - 3584; w = w_proj; wt = wprojT; K = CC; N = CC;
    k0 = (b >> 5) * 64; n0 = (b & 31) * 32;
  }
  const int c = tid & 7, kr0 = tid >> 3;    // (8 float4-chunks, 32 rows)
#pragma unroll
  for (int p = 0; p < 2; p++) {
    int k = kr0 + p * 32;
    float4 v = *(const float4*)&w[(size_t)(k0 + k) * N + n0 + c * 4];
    ushort4 o;
    o.x = bf16_rne(v.x); o.y = bf16_rne(v.y); o.z = bf16_rne(v.z); o.w = bf16_rne(v.w);
    *(ushort4*)&tile[k][c * 4] = o;
  }
  __syncthreads();
  const int kc = tid & 15, nr = tid >> 4;   // (16 k-groups, 16 n-rows)
#pragma unroll
  for (int jn = 0; jn < 2; jn++) {
    int n = nr + (jn << 4);
    ushort4 o;
    o.x = tile[kc * 4 + 0][n];
    o.y = tile[kc * 4 + 1][n];
    o.z = tile[kc * 4 + 2][n];
    o.w = tile[kc * 4 + 3][n];
    *(ushort4*)&wt[(size_t)(n0 + n) * K + k0 + kc * 4] = o;
  }
}

// swizzled frag read: row rr, 8-u16 chunk c8 -> LDS chunk c8 ^ (rr&7)
__device__ __forceinline__ bf16x8 rdsw(const u16* base, int rr, int c8) {
  return ldfrag(&base[rr * 64 + ((c8 ^ (rr & 7)) << 3)]);
}

// ---- qkv GEMM: 128x96 tile (grid 32x16 = 512 blocks = 2/CU), BK=64,
// double-buffered 2-phase (stage(t+1) overlaps compute(t), ONE barrier/iter),
// swizzled LDS, fused RoPE + head-split epilogue; v-slice stored via
// wave-private LDS transpose -> fully coalesced 128B rows ----
__global__ __launch_bounds__(256) void k_gemm_qkv(
    const u16* __restrict__ A, const u16* __restrict__ Bt,
    const float2* __restrict__ scos /*[t][i]*/, u16* __restrict__ qr,
    u16* __restrict__ kr, u16* __restrict__ vt, int M, int N, int K) {
  __shared__ u16 As[2][128 * 64];   // 32 KB, rows of 64 u16, chunk-swizzled
  __shared__ u16 Bs[2][96 * 64];    // 24 KB
  const int tid = threadIdx.x;
  const int lane = tid & 63, w = tid >> 6;
  const int col = lane & 15, quad = lane >> 4;
  const int wm = w >> 1, wn = w & 1;
  const int tm = blockIdx.y * 128, tn = blockIdx.x * 96;

  const int lr = lane >> 3;                    // sub-row 0..7 (swizzle key)
  const int soff = ((lane & 7) ^ lr) << 3;     // u16 offset of source chunk

  f32x4 acc[12];
#pragma unroll
  for (int i = 0; i < 12; i++) acc[i] = (f32x4){0.f, 0.f, 0.f, 0.f};

  auto stage = [&](int k0, int buf) {
#pragma unroll
    for (int i = 0; i < 4; i++) {
      const int rbase = w * 32 + i * 8;
      __builtin_amdgcn_global_load_lds(
          (gv_t*)(A + (size_t)(tm + rbase + lr) * K + k0 + soff),
          (lv_t*)(&As[buf][rbase * 64]), 16, 0, 0);
    }
#pragma unroll
    for (int i = 0; i < 3; i++) {
      const int rbase = w * 24 + i * 8;
      __builtin_amdgcn_global_load_lds(
          (gv_t*)(Bt + (size_t)(tn + rbase + lr) * K + k0 + soff),
          (lv_t*)(&Bs[buf][rbase * 64]), 16, 0, 0);
    }
  };

  stage(0, 0);
  __syncthreads();                             // drain stage(0)
  const int NT = K / 64;                       // 16
  for (int t = 0; t < NT; t++) {
    const int cur = t & 1;
    if (t + 1 < NT) stage((t + 1) * 64, cur ^ 1);  // overlaps compute(t)
#pragma unroll
    for (int kk = 0; kk < 2; kk++) {
      bf16x8 af[4], bf[3];
#pragma unroll
      for (int mt = 0; mt < 4; mt++)
        af[mt] = rdsw(&As[cur][0], wm * 64 + mt * 16 + col, kk * 4 + quad);
#pragma unroll
      for (int nt = 0; nt < 3; nt++)
        bf[nt] = rdsw(&Bs[cur][0], wn * 48 + nt * 16 + col, kk * 4 + quad);
#pragma unroll
      for (int mt = 0; mt < 4; mt++)
#pragma unroll
        for (int nt = 0; nt < 3; nt++)
          acc[mt * 3 + nt] = __builtin_amdgcn_mfma_f32_16x16x32_bf16(af[mt], bf[nt], acc[mt * 3 + nt], 0, 0, 0);
    }
    __syncthreads();                           // drains stage(t+1) after compute
  }
  // After the final barrier every wave is done reading As/Bs -> reuse As as
  // wave-private transpose scratch (16 d x 68-stride u16 per wave = 2176 B).
  u16* scr = ((u16*)As) + w * 1088;

  const int tb = tm + wm * 64;
#pragma unroll
  for (int nt = 0; nt < 3; nt++) {
    const int nn = tn + wn * 48 + nt * 16;     // wave-uniform, 16-aligned
    const int slice = nn >> 10;                // 0=q, 1=k, 2=v (16 | 1024: no straddle)
    const int hh = (nn >> 6) & 15;
    const int db = nn & 63;
    const int d = db + col;
    if (slice < 2) {                           // q/k: RoPE + [H][T][D]
      u16* dst = (slice == 0) ? qr : kr;
      const bool ev = (col & 1) == 0;
      const int i = (db >> 1) + (col >> 1);
#pragma unroll
      for (int mt = 0; mt < 4; mt++)
#pragma unroll
        for (int r = 0; r < 4; r++) {
          int t = tb + mt * 16 + quad * 4 + r;
          float2 sc2 = scos[t * 32 + i];
          float e = acc[mt * 3 + nt][r];
          float pp = __shfl_xor(e, 1);
          float v = ev ? (e * sc2.y - pp * sc2.x) : (pp * sc2.x + e * sc2.y);
          dst[((size_t)(hh * TT + t) << 6) + d] = bf16_rne(v);
        }
    } else {                                   // v: [H][D][T] via LDS transpose
      // write the wave's 16d x 64t sub-tile into scratch [d][t] (stride 68)
#pragma unroll
      for (int mt = 0; mt < 4; mt++)
#pragma unroll
        for (int r = 0; r < 4; r++)
          scr[col * 68 + mt * 16 + quad * 4 + r] = bf16_rne(acc[mt * 3 + nt][r]);
      // same-wave ds_write->ds_read ordering handled by lgkmcnt (no barrier:
      // scratch is wave-private)
#pragma unroll
      for (int i = 0; i < 4; i++) {
        const int dl = quad + i * 4;           // row 0..15 (one row per 16 lanes)
        const int tl = col * 4;                // 0..60
        ushort4 vv = *(const ushort4*)&scr[dl * 68 + tl];
        *(ushort4*)&vt[((size_t)(hh * DD + db + dl)) * TT + tb + tl] = vv;
      }
    }
  }
}

// ---- proj GEMM: 32x64 tile (grid 16x64 = 1024 blocks = 4/CU, LDS 24 KB),
// BK=64, double-buffered 2-phase, swizzled LDS, fp32 out. Wave tile 16x32. ----
__global__ __launch_bounds__(256) void k_gemm_pj(
    const u16* __restrict__ A, const u16* __restrict__ Bt,
    float* __restrict__ C, int M, int N, int K) {
  __shared__ u16 As[2][32 * 64];    //  8 KB
  __shared__ u16 Bs[2][64 * 64];    // 16 KB
  const int tid = threadIdx.x;
  const int lane = tid & 63, w = tid >> 6;
  const int col = lane & 15, quad = lane >> 4;
  const int wm = w >> 1, wn = w & 1;
  const int tm = blockIdx.y * 32, tn = blockIdx.x * 64;

  const int lr = lane >> 3;
  const int soff = ((lane & 7) ^ lr) << 3;

  f32x4 acc[2];
#pragma unroll
  for (int i = 0; i < 2; i++) acc[i] = (f32x4){0.f, 0.f, 0.f, 0.f};

  auto stage = [&](int k0, int buf) {
    {                                          // A: 32 rows, 8 rows/wave
      const int rbase = w * 8;
      __builtin_amdgcn_global_load_lds(
          (gv_t*)(A + (size_t)(tm + rbase + lr) * K + k0 + soff),
          (lv_t*)(&As[buf][rbase * 64]), 16, 0, 0);
    }
#pragma unroll
    for (int i = 0; i < 2; i++) {              // B: 64 rows, 16 rows/wave
      const int rbase = w * 16 + i * 8;
      __builtin_amdgcn_global_load_lds(
          (gv_t*)(Bt + (size_t)(tn + rbase + lr) * K + k0 + soff),
          (lv_t*)(&Bs[buf][rbase * 64]), 16, 0, 0);
    }
  };

  stage(0, 0);
  __syncthreads();
  const int NT = K / 64;
  for (int t = 0; t < NT; t++) {
    const int cur = t & 1;
    if (t + 1 < NT) stage((t + 1) * 64, cur ^ 1);
#pragma unroll
    for (int kk = 0; kk < 2; kk++) {
      bf16x8 af = rdsw(&As[cur][0], wm * 16 + col, kk * 4 + quad);
      bf16x8 bf[2];
#pragma unroll
      for (int nt = 0; nt < 2; nt++)
        bf[nt] = rdsw(&Bs[cur][0], wn * 32 + nt * 16 + col, kk * 4 + quad);
#pragma unroll
      for (int nt = 0; nt < 2; nt++)
        acc[nt] = __builtin_amdgcn_mfma_f32_16x16x32_bf16(af, bf[nt], acc[nt], 0, 0, 0);
    }
    __syncthreads();
  }
#pragma unroll
  for (int nt = 0; nt < 2; nt++)
#pragma unroll
    for (int r = 0; r < 4; r++)
      C[(size_t)(tm + wm * 16 + quad * 4 + r) * N + tn + wn * 32 + nt * 16 + col] =
          acc[nt][r];
}

// ---- cooperative flash: 1024 blocks = (head, 32-query strip) -> 4 blocks/CU,
// 16 waves/CU; waves split (q-half x key-parity), partial (acc,l) merged via
// LDS (fixed-offset softmax => exact associativity). l computed on the MFMA
// pipe (B = ones). K AND V staged via global_load_lds (register loads from
// L2 regress: R6/R12). ----
__global__ __launch_bounds__(256) void k_flash(
    const u16* __restrict__ qr, const u16* __restrict__ kr,
    const u16* __restrict__ vt, u16* __restrict__ attnb /*[T][C]*/) {
  __shared__ u16 Ks[2][64 * 64];      // 16 KB: [parity] 64-key tile
  __shared__ u16 Vs[2][64 * 64];      // 16 KB: [parity] ([d][t])
  __shared__ u16 Ps[4][16 * 64];      //  8 KB, wave-private slices

  const int tid = threadIdx.x;
  const int lane = tid & 63, wv = tid >> 6;
  const int col = lane & 15, quad = lane >> 4;

  // balanced block -> (head, 32-q strip): CU c gets ranks {c,63-c,64+c,127-c}
  const int bid = blockIdx.x;                  // 1024 blocks
  const int xcd = bid & 7, slot = bid >> 3;    // slot 0..127
  const int cu = slot & 31, tier = slot >> 5;  // tier 0..3
  const int rank = (tier & 1) ? (tier * 32 + (31 - cu)) : (tier * 32 + cu);
  const int h = xcd * 2 + (rank & 1);
  const int s = rank >> 1;                     // strip 0..63
  const int q0 = s * 32;
  const int nkt = (s >> 1) + 1;                // 64-key tiles covering 0..q0+31
  const int tdiag = s >> 1;                    // only tile needing the mask

  const int qh = wv & 1;                       // q-half (rows q0+qh*16..+16)
  const int kp = wv >> 1;                      // key parity (tiles 2w+kp)

  const u16* Qh = qr + (size_t)h * TT * DD;
  const u16* Kh = kr + (size_t)h * TT * DD;
  const u16* Vh = vt + (size_t)h * DD * TT;    // [d][t]

  const bf16x8 aq0 = ldfrag(&Qh[(size_t)(q0 + qh * 16 + col) * DD + quad * 8]);
  const bf16x8 aq1 = ldfrag(&Qh[(size_t)(q0 + qh * 16 + col) * DD + 32 + quad * 8]);
  const bf16x8 vones = __builtin_bit_cast(bf16x8,
      (u16x8){0x3F80, 0x3F80, 0x3F80, 0x3F80, 0x3F80, 0x3F80, 0x3F80, 0x3F80});

  const int lr = lane >> 3;                    // sub-row 0..7 (swizzle key)
  const int srcoff = ((lane & 7) ^ lr) << 3;

  const f32x4 zero = {0.f, 0.f, 0.f, 0.f};
  f32x4 acc[4] = {zero, zero, zero, zero};
  f32x4 lacc = zero;                           // l[q] on the matrix pipe
  u16* Pb = &Ps[wv][0];

  auto compute = [&](int t, const u16* Kt, const u16* Vt) {
    // S = Q K^T
    f32x4 sc[4];
#pragma unroll
    for (int nt = 0; nt < 4; nt++) {
      const int rr = nt * 16 + col;
      sc[nt] = __builtin_amdgcn_mfma_f32_16x16x32_bf16(aq0, rdsw(Kt, rr, quad), zero, 0, 0, 0);
      sc[nt] = __builtin_amdgcn_mfma_f32_16x16x32_bf16(aq1, rdsw(Kt, rr, 4 + quad), sc[nt], 0, 0, 0);
    }
    if (t == tdiag) {                          // causal mask on the edge tile
#pragma unroll
      for (int nt = 0; nt < 4; nt++)
#pragma unroll
        for (int r = 0; r < 4; r++)
          if (t * 64 + nt * 16 + col > q0 + qh * 16 + quad * 4 + r) sc[nt][r] = -1e30f;
    }
    // p = exp(s/8 - 20) via exp2
#pragma unroll
    for (int nt = 0; nt < 4; nt++)
#pragma unroll
      for (int r = 0; r < 4; r++)
        sc[nt][r] = exp2f(fmaf(sc[nt][r], 0.18033688f, -28.8539008f));
    // P -> LDS (C-layout scatter, XOR bank swizzle on 16-col blocks)
#pragma unroll
    for (int nt = 0; nt < 4; nt++) {
      unsigned p01 = pk_bf16(sc[nt][0], sc[nt][1]);
      unsigned p23 = pk_bf16(sc[nt][2], sc[nt][3]);
      u16* base = Pb + quad * 4 * 64 + ((nt ^ quad) << 4) + col;
      base[0 * 64] = (u16)p01;
      base[1 * 64] = (u16)(p01 >> 16);
      base[2 * 64] = (u16)p23;
      base[3 * 64] = (u16)(p23 >> 16);
    }
    // O += P V^T ; l += P . 1 (extra MFMA with B = ones, MFMA pipe is idle)
#pragma unroll
    for (int kk = 0; kk < 2; kk++) {
      int sb = (kk * 2 + (quad >> 1)) ^ (col >> 2);
      bf16x8 ap = ldfrag(&Pb[col * 64 + (sb << 4) + ((quad & 1) << 3)]);
#pragma unroll
      for (int nt = 0; nt < 4; nt++)
        acc[nt] = __builtin_amdgcn_mfma_f32_16x16x32_bf16(
            ap, rdsw(Vt, nt * 16 + col, kk * 4 + quad), acc[nt], 0, 0, 0);
      lacc = __builtin_amdgcn_mfma_f32_16x16x32_bf16(ap, vones, lacc, 0, 0, 0);
    }
  };

  const int nw = (nkt + 1) >> 1;               // 2-tile windows
  for (int w = 0; w < nw; w++) {
    __syncthreads();                           // prior compute done with Ks/Vs
#pragma unroll
    for (int j = 0; j < 2; j++) {              // stage tiles 2w, 2w+1
      const int t = 2 * w + j;
      if (t < nkt) {
#pragma unroll
        for (int i = 0; i < 2; i++) {
          const int rbase = wv * 16 + i * 8;
          __builtin_amdgcn_global_load_lds(
              (gv_t*)(Kh + (size_t)(t * 64 + rbase + lr) * DD + srcoff),
              (lv_t*)(&Ks[j][rbase * 64]), 16, 0, 0);
          __builtin_amdgcn_global_load_lds(
              (gv_t*)(Vh + (size_t)(rbase + lr) * TT + t * 64 + srcoff),
              (lv_t*)(&Vs[j][rbase * 64]), 16, 0, 0);
        }
      }
    }
    __syncthreads();                           // staged (vmcnt drained)
    const int t = 2 * w + kp;
    if (t < nkt) compute(t, Ks[kp], Vs[kp]);
  }

  // merge key-parity partials: waves 2,3 -> waves 0,1 (plain sums: associative)
  float* mbuf = (float*)&Ks[0][0];             // 2 x 1344 floats <= 16 KB
  __syncthreads();                             // computes done; Ks reusable
  if (kp == 1) {
    float* mb = mbuf + qh * 1344;
#pragma unroll
    for (int i = 0; i < 4; i++)
#pragma unroll
      for (int r = 0; r < 4; r++) mb[lane * 20 + i * 4 + r] = acc[i][r];
#pragma unroll
    for (int r = 0; r < 4; r++) mb[lane * 20 + 16 + r] = lacc[r];
  }
  __syncthreads();
  if (kp == 0) {
    float* mb = mbuf + qh * 1344;
#pragma unroll
    for (int i = 0; i < 4; i++)
#pragma unroll
      for (int r = 0; r < 4; r++) acc[i][r] += mb[lane * 20 + i * 4 + r];
#pragma unroll
    for (int r = 0; r < 4; r++) lacc[r] += mb[lane * 20 + 16 + r];
    // lacc already holds the full row sum (MFMA summed all 64 keys/tile,
    // replicated across cols) -> no shfl reduce needed
    float inv[4];
#pragma unroll
    for (int r = 0; r < 4; r++) inv[r] = 1.f / lacc[r];
#pragma unroll
    for (int nt = 0; nt < 4; nt++)
#pragma unroll
      for (int r = 0; r < 4; r++) {
        int q = q0 + qh * 16 + quad * 4 + r;
        attnb[(size_t)q * CC + h * DD + nt * 16 + col] = bf16_rne(acc[nt][r] * inv[r]);
      }
  }
}

extern "C" void kernel_launch(void* const* d_in, const int* in_sizes, int n_in,
                              void* d_out, int out_size, void* d_ws, size_t ws_size,
                              hipStream_t stream) {
  const float* x      = (const float*)d_in[0];  // [2048][1024]
  const float* w_qkv  = (const float*)d_in[1];  // [1024][3072]
  const float* w_proj = (const float*)d_in[2];  // [1024][1024]
  float* out = (float*)d_out;                   // [2048][1024] fp32

  char* p = (char*)d_ws;
  u16* xb      = (u16*)p;    p += (size_t)TT * CC * 2;
  u16* wqkvT   = (u16*)p;    p += (size_t)N3 * CC * 2;
  u16* wprojT  = (u16*)p;    p += (size_t)CC * CC * 2;
  float2* scos = (float2*)p; p += (size_t)TT * 32 * 8;
  u16* qr      = (u16*)p;    p += (size_t)HH * TT * DD * 2;
  u16* kr      = (u16*)p;    p += (size_t)HH * TT * DD * 2;
  u16* vt      = (u16*)p;    p += (size_t)HH * DD * TT * 2;
  u16* attnb   = (u16*)p;    p += (size_t)TT * CC * 2;

  k_prep<<<2048 + 1536 + 512 + 256, 256, 0, stream>>>(x, w_qkv, w_proj, xb, wqkvT, wprojT, scos);
  k_gemm_qkv<<<dim3(N3 / 96, TT / 128), 256, 0, stream>>>(xb, wqkvT, scos, qr, kr, vt, TT, N3, CC);
  k_flash<<<1024, 256, 0, stream>>>(qr, kr, vt, attnb);
  k_gemm_pj<<<dim3(CC / 64, TT / 32), 256, 0, stream>>>(attnb, wprojT, out, TT, CC, CC);
}